// Round 6
// baseline (599.634 us; speedup 1.0000x reference)
//
#include <hip/hip_runtime.h>

__device__ __forceinline__ float u2f(unsigned short u) {
  union { unsigned int i; float f; } v; v.i = ((unsigned)u) << 16; return v.f;
}
__device__ __forceinline__ unsigned short f2u(float f) {
  union { float f; unsigned int i; } v; v.f = f;
  unsigned int x = v.i;
  return (unsigned short)((x + 0x7fffu + ((x >> 16) & 1u)) >> 16);  // RNE bf16
}

__device__ __forceinline__ void decode_hw(const void* Hp, const void* Wp, int& H, int& W) {
  long long h = ((const int*)Hp)[0], w = ((const int*)Wp)[0];
  if (h >= 1 && h <= 16384 && w >= 1 && w <= 16384 && h * w == 16384) { H = (int)h; W = (int)w; return; }
  float fh = ((const float*)Hp)[0], fw = ((const float*)Wp)[0];
  if (fh >= 1.f && fh <= 16384.f && fw >= 1.f && fw <= 16384.f &&
      (long long)fh * (long long)fw == 16384) { H = (int)fh; W = (int)fw; return; }
  H = 128; W = 128;
}

// ---------------- GEMM: C[M,N] = A[M,K] @ B[K,N](fp32) + bias(fp32) ---------
// aBf16: A is packed bf16 (internal staging) else fp32. outBf16 likewise.
// Tile 64x64, K-chunk 64; 256 threads; 4x4 fp32 acc each.
#define TM 64
#define TN 64
#define TKC 64

__launch_bounds__(256)
__global__ void gemm_bias_kernel(const void* __restrict__ A, int aBf16,
                                 const float* __restrict__ B,
                                 const float* __restrict__ bias,
                                 void* __restrict__ C, int outBf16,
                                 int M, int N, int K)
{
  __shared__ __align__(16) float AsT[TKC][TM + 4];  // [k][m]
  __shared__ __align__(16) float Bs[TKC][TN + 4];   // [k][n]
  const int tid = threadIdx.x;
  const int tx = tid & 15, ty = tid >> 4;
  const int m0 = blockIdx.y * TM, n0 = blockIdx.x * TN;
  float acc[4][4] = {};

  for (int k0 = 0; k0 < K; k0 += TKC) {
    #pragma unroll
    for (int i = 0; i < 8; ++i) {
      int e = (tid + i * 256) * 2;
      int mr = e >> 6, kc = e & 63;
      size_t idx = (size_t)(m0 + mr) * K + (k0 + kc);
      float2 a;
      if (aBf16) {
        ushort2 u = *(const ushort2*)((const unsigned short*)A + idx);
        a = make_float2(u2f(u.x), u2f(u.y));
      } else {
        a = *(const float2*)((const float*)A + idx);
      }
      AsT[kc][mr]     = a.x;
      AsT[kc + 1][mr] = a.y;
    }
    #pragma unroll
    for (int i = 0; i < 8; ++i) {
      int e = (tid + i * 256) * 2;
      int kr = e >> 6, nc = e & 63;
      float2 b2 = *(const float2*)(B + (size_t)(k0 + kr) * N + (n0 + nc));
      Bs[kr][nc] = b2.x; Bs[kr][nc + 1] = b2.y;
    }
    __syncthreads();
    #pragma unroll 8
    for (int kk = 0; kk < TKC; ++kk) {
      float4 av = *(const float4*)&AsT[kk][ty * 4];
      float4 bv = *(const float4*)&Bs[kk][tx * 4];
      float aa[4] = {av.x, av.y, av.z, av.w};
      float bb[4] = {bv.x, bv.y, bv.z, bv.w};
      #pragma unroll
      for (int i = 0; i < 4; ++i)
        #pragma unroll
        for (int j = 0; j < 4; ++j)
          acc[i][j] += aa[i] * bb[j];
    }
    __syncthreads();
  }

  #pragma unroll
  for (int i = 0; i < 4; ++i) {
    int row = m0 + ty * 4 + i;
    #pragma unroll
    for (int j = 0; j < 4; ++j) {
      int col = n0 + tx * 4 + j;
      float v = acc[i][j] + bias[col];
      if (outBf16) ((unsigned short*)C)[(size_t)row * N + col] = f2u(v);
      else         ((float*)C)[(size_t)row * N + col] = v;
    }
  }
}

// -------- Fused: off/logits mini-GEMM + softmax + bilinear sampling ---------
// Block handles RQ=8 queries. Phase 1: threads 0..95 compute off(64)+logits(32)
// per row from an LDS tgt tile. Phase 2: thread=(h,c) samples all 8 rows.
#define RQ 8
__launch_bounds__(256)
__global__ void sample_kernel(const unsigned short* __restrict__ value, // (B,S,NH,DH) bf16
                              const float* __restrict__ tgt,            // (B*LQ,256)
                              const float* __restrict__ refp,           // (B*LQ,2)
                              const float* __restrict__ Woff,           // (256,64)
                              const float* __restrict__ boff,           // (64)
                              const float* __restrict__ Wattn,          // (256,32)
                              const float* __restrict__ battn,          // (32)
                              unsigned short* __restrict__ out,         // (B*LQ,256) bf16
                              const void* __restrict__ Hp,
                              const void* __restrict__ Wp)
{
  int H, W; decode_hw(Hp, Wp, H, W);
  const int S = H * W;
  __shared__ __align__(16) float tgt_s[RQ][260];
  __shared__ float off_s[RQ][64];
  __shared__ float lg_s[RQ][36];
  __shared__ float ref_s[RQ][2];
  const int tid = threadIdx.x;
  const int r0 = blockIdx.x * RQ;

  for (int idx = tid; idx < RQ * 64; idx += 256) {
    int row = idx >> 6, col4 = (idx & 63) * 4;
    *(float4*)&tgt_s[row][col4] = *(const float4*)(tgt + (size_t)(r0 + row) * 256 + col4);
  }
  if (tid < RQ * 2)
    ref_s[tid >> 1][tid & 1] = refp[(size_t)(r0 + (tid >> 1)) * 2 + (tid & 1)];
  __syncthreads();

  if (tid < 96) {
    const float* Wm; const float* bm; int ncol, jj;
    if (tid < 64) { Wm = Woff;  bm = boff;  ncol = 64; jj = tid; }
    else          { Wm = Wattn; bm = battn; ncol = 32; jj = tid - 64; }
    float acc[RQ];
    #pragma unroll
    for (int row = 0; row < RQ; ++row) acc[row] = 0.f;
    for (int k = 0; k < 256; k += 4) {
      float w0 = Wm[(size_t)(k + 0) * ncol + jj];
      float w1 = Wm[(size_t)(k + 1) * ncol + jj];
      float w2 = Wm[(size_t)(k + 2) * ncol + jj];
      float w3 = Wm[(size_t)(k + 3) * ncol + jj];
      #pragma unroll
      for (int row = 0; row < RQ; ++row) {
        float4 tv = *(const float4*)&tgt_s[row][k];
        acc[row] += tv.x * w0 + tv.y * w1 + tv.z * w2 + tv.w * w3;
      }
    }
    float bb = bm[jj];
    #pragma unroll
    for (int row = 0; row < RQ; ++row) {
      float o = acc[row] + bb;
      if (tid < 64) off_s[row][jj] = o; else lg_s[row][jj] = o;
    }
  }
  __syncthreads();

  const int h = tid >> 5, c = tid & 31;
  const int b = r0 >> 13;                 // LQ = 8192
  const size_t vbase = (size_t)b * S * 256;
  for (int row = 0; row < RQ; ++row) {
    const int r = r0 + row;
    float lg[4];
    #pragma unroll
    for (int p = 0; p < 4; ++p) lg[p] = lg_s[row][h * 4 + p];
    float mx = fmaxf(fmaxf(lg[0], lg[1]), fmaxf(lg[2], lg[3]));
    float sum = 0.f;
    #pragma unroll
    for (int p = 0; p < 4; ++p) { lg[p] = __expf(lg[p] - mx); sum += lg[p]; }
    const float inv = 1.f / sum;
    const float rx = ref_s[row][0], ry = ref_s[row][1];
    float acc = 0.f;
    #pragma unroll
    for (int p = 0; p < 4; ++p) {
      const float x = rx * (float)W + off_s[row][h * 8 + p * 2 + 0] - 0.5f;
      const float y = ry * (float)H + off_s[row][h * 8 + p * 2 + 1] - 0.5f;
      const float xf = floorf(x), yf = floorf(y);
      const float wx = x - xf, wy = y - yf;
      const int x0 = (int)xf, y0 = (int)yf;
      float sp = 0.f;
      #pragma unroll
      for (int dy = 0; dy < 2; ++dy)
        #pragma unroll
        for (int dx = 0; dx < 2; ++dx) {
          const int yy = y0 + dy, xx = x0 + dx;
          if ((unsigned)yy < (unsigned)H && (unsigned)xx < (unsigned)W) {
            const float wgt = (dy ? wy : 1.f - wy) * (dx ? wx : 1.f - wx);
            sp += wgt * u2f(value[vbase + (size_t)(yy * W + xx) * 256 + h * 32 + c]);
          }
        }
      acc += lg[p] * inv * sp;
    }
    out[(size_t)r * 256 + h * 32 + c] = f2u(acc);
  }
}

// ---------------- Residual + LayerNorm (D=256), wave per row ----------------
// y = LN(A + B2)*g + b, all fp32. If B2==A this is LN(2A).
__launch_bounds__(256)
__global__ void ln_kernel(const float* __restrict__ A,
                          const float* __restrict__ B2,
                          const float* __restrict__ g,
                          const float* __restrict__ be,
                          float* __restrict__ out)
{
  const size_t row = (size_t)blockIdx.x * 4 + (threadIdx.x >> 6);
  const int lane = threadIdx.x & 63;
  const size_t base = row * 256 + lane * 4;
  const float4 xa = *(const float4*)(A + base);
  const float4 xb = *(const float4*)(B2 + base);
  float x[4];
  x[0] = xa.x + xb.x; x[1] = xa.y + xb.y; x[2] = xa.z + xb.z; x[3] = xa.w + xb.w;
  float s = x[0] + x[1] + x[2] + x[3];
  float sq = x[0]*x[0] + x[1]*x[1] + x[2]*x[2] + x[3]*x[3];
  #pragma unroll
  for (int off = 32; off; off >>= 1) {
    s  += __shfl_xor(s, off);
    sq += __shfl_xor(sq, off);
  }
  const float mean = s * (1.f / 256.f);
  const float var = sq * (1.f / 256.f) - mean * mean;
  const float rstd = rsqrtf(var + 1e-5f);
  const float4 gg = *(const float4*)(g + lane * 4);
  const float4 bb = *(const float4*)(be + lane * 4);
  float4 o;
  o.x = (x[0] - mean) * rstd * gg.x + bb.x;
  o.y = (x[1] - mean) * rstd * gg.y + bb.y;
  o.z = (x[2] - mean) * rstd * gg.z + bb.z;
  o.w = (x[3] - mean) * rstd * gg.w + bb.w;
  *(float4*)(out + base) = o;
}

extern "C" void kernel_launch(void* const* d_in, const int* in_sizes, int n_in,
                              void* d_out, int out_size, void* d_ws, size_t ws_size,
                              hipStream_t stream) {
  const float* tgt  = (const float*)d_in[0];
  const float* src  = (const float*)d_in[1];
  const float* refp = (const float*)d_in[2];
  const float* Wv   = (const float*)d_in[3];
  const float* bv   = (const float*)d_in[4];
  const float* Wo   = (const float*)d_in[5];
  const float* bo   = (const float*)d_in[6];
  const float* Wa   = (const float*)d_in[7];
  const float* ba   = (const float*)d_in[8];
  const float* Wout = (const float*)d_in[9];
  const float* bout = (const float*)d_in[10];
  const float* g1   = (const float*)d_in[11];
  const float* b1   = (const float*)d_in[12];
  const float* g2   = (const float*)d_in[13];
  const float* b2   = (const float*)d_in[14];
  const void* Hp    = d_in[15];
  const void* Wp    = d_in[16];

  // d_out: fp32, [query 8388608 | src_out 16777216] elements.
  float* q_out = (float*)d_out;
  float* s_out = q_out + (size_t)8388608;

  // Staging:
  //   value   : ws, bf16, 16777216 elems (33.5 MB; ws >= 46 MB proven in R3)
  //   sampled : d_out[0:8388608) region reinterpreted as bf16 (dead until ln6)
  //   attn_out: d_out fp32 [8388608, 16777216) (dead until ln7; ln6 consumes it)
  unsigned short* value   = (unsigned short*)d_ws;
  unsigned short* sampled = (unsigned short*)d_out;
  float*          aobuf   = q_out + (size_t)8388608;

  dim3 blk(256);
  // 1. value = src @ W_value + b_value   (65536 x 256 x 256) -> bf16 ws
  gemm_bias_kernel<<<dim3(4, 1024), blk, 0, stream>>>(src, 0, Wv, bv, value, 1, 65536, 256, 256);
  // 2. fused off/logits + softmax + bilinear sampling -> sampled (bf16 in q region)
  sample_kernel<<<dim3(32768 / RQ), blk, 0, stream>>>(value, tgt, refp, Wo, bo, Wa, ba,
                                                      sampled, Hp, Wp);
  // 3. attn_out = sampled @ W_out + b_out (32768 x 256 x 256) -> fp32 in s region
  gemm_bias_kernel<<<dim3(4, 512), blk, 0, stream>>>(sampled, 1, Wout, bout, aobuf, 0, 32768, 256, 256);
  // 4. query = LN(tgt + attn_out) -> q_out (overwrites dead sampled)
  ln_kernel<<<dim3(8192), blk, 0, stream>>>(tgt, aobuf, g1, b1, q_out);
  // 5. src_out = LN(src + src) -> s_out (overwrites dead attn_out)
  ln_kernel<<<dim3(16384), blk, 0, stream>>>(src, src, g2, b2, s_out);
}